// Round 11
// baseline (1949.140 us; speedup 1.0000x reference)
//
#include <hip/hip_runtime.h>

#define B_    64
#define T_    1024
#define H_    1024
#define HALF_ 512
#define NWG_SCAN 128
#define NWG_GEMM_REST 3072
#define HBUF_HALF 131072   // shorts per double-buffer half: 2*64*1024

typedef short bf16x8 __attribute__((ext_vector_type(8)));
typedef short bf16x4 __attribute__((ext_vector_type(4)));
typedef _Float16 f16x8 __attribute__((ext_vector_type(8)));
typedef float f32x4  __attribute__((ext_vector_type(4)));
typedef unsigned int u32x4 __attribute__((ext_vector_type(4)));

__device__ __forceinline__ short f2bf(float f) {
    unsigned u = __builtin_bit_cast(unsigned, f);
    u += 0x7fffu + ((u >> 16) & 1u);
    return (short)(u >> 16);
}

__device__ __forceinline__ short f2h(float f) {
    return (short)__builtin_bit_cast(unsigned short, (_Float16)f);
}

__device__ __forceinline__ float tanh_fast(float x) {
    return 1.0f - 2.0f / (__expf(2.0f * x) + 1.0f);
}

// LDS-only barrier: no vmcnt drain.
#define BAR() do { \
    __builtin_amdgcn_sched_barrier(0); \
    asm volatile("s_waitcnt lgkmcnt(0)" ::: "memory"); \
    __builtin_amdgcn_sched_barrier(0); \
    __builtin_amdgcn_s_barrier(); \
    __builtin_amdgcn_sched_barrier(0); \
} while (0)

// GEMM tile body shared by pre_gemm and the fused gemm role.
// Computes gi tile (tm,tn) of gi = bf16(x)@bf16(Wih)^T + bias into acc.
#define GEMM_TILE_BODY(As_, Bs_)                                               \
    const float* Ab = X   + (size_t)tm * 128 * 1024;                           \
    const float* Bb = Wih + (size_t)tn * 128 * 1024;                           \
    const int srow = tid >> 3;                                                 \
    const int sc4  = (tid & 7) * 4;                                            \
    f32x4 acc[4][4];                                                           \
    _Pragma("unroll")                                                          \
    for (int m = 0; m < 4; m++)                                                \
        _Pragma("unroll")                                                      \
        for (int n = 0; n < 4; n++) acc[m][n] = (f32x4){0.f, 0.f, 0.f, 0.f};   \
    f32x4 ra[4], rb[4];                                                        \
    _Pragma("unroll")                                                          \
    for (int c = 0; c < 4; c++) {                                              \
        ra[c] = *reinterpret_cast<const f32x4*>(Ab + (size_t)(srow + 32*c) * 1024 + sc4); \
        rb[c] = *reinterpret_cast<const f32x4*>(Bb + (size_t)(srow + 32*c) * 1024 + sc4); \
    }                                                                          \
    for (int k0 = 0; k0 < 1024; k0 += 32) {                                    \
        __syncthreads();                                                       \
        _Pragma("unroll")                                                      \
        for (int c = 0; c < 4; c++) {                                          \
            bf16x4 va = { f2bf(ra[c].x), f2bf(ra[c].y), f2bf(ra[c].z), f2bf(ra[c].w) }; \
            bf16x4 vb = { f2bf(rb[c].x), f2bf(rb[c].y), f2bf(rb[c].z), f2bf(rb[c].w) }; \
            *reinterpret_cast<bf16x4*>(&As_[srow + 32*c][sc4]) = va;           \
            *reinterpret_cast<bf16x4*>(&Bs_[srow + 32*c][sc4]) = vb;           \
        }                                                                      \
        __syncthreads();                                                       \
        if (k0 + 32 < 1024) {                                                  \
            const float* Ak = Ab + k0 + 32;                                    \
            const float* Bk = Bb + k0 + 32;                                    \
            _Pragma("unroll")                                                  \
            for (int c = 0; c < 4; c++) {                                      \
                ra[c] = *reinterpret_cast<const f32x4*>(Ak + (size_t)(srow + 32*c) * 1024 + sc4); \
                rb[c] = *reinterpret_cast<const f32x4*>(Bk + (size_t)(srow + 32*c) * 1024 + sc4); \
            }                                                                  \
        }                                                                      \
        bf16x8 af[4], bfr[4];                                                  \
        _Pragma("unroll")                                                      \
        for (int m = 0; m < 4; m++)                                            \
            af[m] = *reinterpret_cast<bf16x8*>(&As_[wr*64 + m*16 + lc][lr*8]); \
        _Pragma("unroll")                                                      \
        for (int n = 0; n < 4; n++)                                            \
            bfr[n] = *reinterpret_cast<bf16x8*>(&Bs_[wc*64 + n*16 + lc][lr*8]); \
        _Pragma("unroll")                                                      \
        for (int m = 0; m < 4; m++)                                            \
            _Pragma("unroll")                                                  \
            for (int n = 0; n < 4; n++)                                        \
                acc[m][n] = __builtin_amdgcn_mfma_f32_16x16x32_bf16(af[m], bfr[n], acc[m][n], 0, 0, 0); \
    }

// ---------------- Phase 1a: serial pre-GEMM for t-chunks {0, 7} --------------
// Produces gi for t in [0,128) u [896,1024): the scan's two entry points
// (even chain t=0.., odd chain t=1023). LSB-tagged plain stores; kernel
// boundary guarantees visibility to the fused kernel.
__global__ __launch_bounds__(256) void pre_gemm(
        const float* __restrict__ X, const float* __restrict__ Wih,
        const float* __restrict__ bih, const float* __restrict__ bhh,
        float* __restrict__ out) {
    __shared__ short As[128][40];
    __shared__ short Bs[128][40];
    const int bid = blockIdx.x;
    const int tn = bid & 7;
    const int q  = bid >> 3;           // 0..127
    const int b_ = q & 63;
    const int kc_ = (q >> 6) ? 7 : 0;  // chunk 0 first, then chunk 7
    const int tm = b_ * 8 + kc_;
    const int tid = threadIdx.x;
    const int l  = tid & 63;
    const int w  = tid >> 6;
    const int wr = w >> 1, wc = w & 1;
    const int lc = l & 15,  lr = l >> 4;

    GEMM_TILE_BODY(As, Bs)

#pragma unroll
    for (int n = 0; n < 4; n++) {
        const int col = tn*128 + wc*64 + n*16 + lc;
        const float bs = bih[col] + bhh[col];
#pragma unroll
        for (int m = 0; m < 4; m++) {
            const int row0 = tm*128 + wr*64 + m*16 + lr*4;
#pragma unroll
            for (int j = 0; j < 4; j++) {
                float v = acc[m][n][j] + bs;
                unsigned uv = __builtin_bit_cast(unsigned, v) | 1u;   // ready tag
                out[(size_t)(row0 + j) * 1024 + col] = __builtin_bit_cast(float, uv);
            }
        }
    }
}

// ---------------------------------------------------------------------------
// Fused kernel with CU fencing: EVERY block statically allocates 144 KB LDS,
// so exactly 1 block fits per CU (2x144 > 160 KB). The 128 scan blocks
// (dispatched first) each own a private CU -> no issue-slot/L1 contention
// with gemm blocks (R9's failure mode). The 3072 gemm blocks fill the OTHER
// 128 CUs, producing t-chunks 1..6 ascending with LSB-tagged sc0 sc1 stores;
// production (~120us/chunk at occupancy-1) permanently outruns consumption
// (200us/chunk). Scan role is R9's passed code verbatim. No deadlock path:
// gemm never waits; scan spin is bounded by gemm completion.
// ---------------------------------------------------------------------------
__global__ __launch_bounds__(256, 1) void fused_rnn(
        const float* __restrict__ X, const float* __restrict__ Wih,
        const float* __restrict__ bih, const float* __restrict__ bhh,
        const float* __restrict__ Whh, float* __restrict__ out,
        short* __restrict__ hbuf) {
    __shared__ __align__(16) char smem[147456];   // 144 KB -> 1 block/CU fence
    const int tid = threadIdx.x;

    if (blockIdx.x >= NWG_SCAN) {
        // ===================== GEMM role: chunks 1..6 =====================
        short (*As)[40] = reinterpret_cast<short(*)[40]>(smem);
        short (*Bs)[40] = reinterpret_cast<short(*)[40]>(smem + 10240);
        const int gb = blockIdx.x - NWG_SCAN;   // 0..3071
        const int tn = gb & 7;
        const int u_ = gb >> 3;                 // 0..383
        const int b_ = u_ & 63;
        const int j_ = u_ >> 6;                 // 0..5 -> chunk j_+1
        const int tm = b_ * 8 + (j_ + 1);
        const int l  = tid & 63;
        const int w  = tid >> 6;
        const int wr = w >> 1, wc = w & 1;
        const int lc = l & 15,  lr = l >> 4;

        GEMM_TILE_BODY(As, Bs)

        // LSB-tagged device-scope stores (gi readiness flag, same-kernel vis)
#pragma unroll
        for (int n = 0; n < 4; n++) {
            const int col = tn*128 + wc*64 + n*16 + lc;
            const float bs = bih[col] + bhh[col];
#pragma unroll
            for (int m = 0; m < 4; m++) {
                const int row0 = tm*128 + wr*64 + m*16 + lr*4;
#pragma unroll
                for (int j = 0; j < 4; j++) {
                    float v = acc[m][n][j] + bs;
                    unsigned uv = __builtin_bit_cast(unsigned, v) | 1u;
                    float* op_ = out + (size_t)(row0 + j) * 1024 + col;
                    asm volatile("global_store_dword %0, %1, off sc0 sc1"
                                 :: "v"(op_), "v"(uv) : "memory");
                }
            }
        }
        return;
    }

    // ===================== SCAN role (R9 passed code) =====================
    short* hB   = reinterpret_cast<short*>(smem);            // 32768 B, swizzled
    short* htr  = reinterpret_cast<short*>(smem + 32768);    // 2176 B
    float* htrF = reinterpret_cast<float*>(smem + 34944);    // 4352 B
    const int wg = blockIdx.x;
    const int p  = wg >> 6;           // parity
    const int g  = (wg >> 4) & 3;     // batch group (16 batches)
    const int s  = wg & 15;           // col slice (64 cols)
    const int l  = tid & 63;
    const int w  = tid >> 6;
    const int lc = l & 15, lr = l >> 4;
    const int sb = tid >> 4;          // staging batch row 0..15
    const int sg = tid & 15;          // staging granule index

    // W_hh rows [s*64 + w*16 + lc], fp32 -> fp16, direct to 128 VGPRs
    bf16x8 breg[32];
    {
        const float* wrow = Whh + (size_t)(s*64 + w*16 + lc) * 1024;
#pragma unroll
        for (int kc = 0; kc < 32; kc++) {
            f32x4 v0 = *reinterpret_cast<const f32x4*>(wrow + kc*32 + lr*8);
            f32x4 v1 = *reinterpret_cast<const f32x4*>(wrow + kc*32 + lr*8 + 4);
            bf16x8 q = { f2h(v0.x), f2h(v0.y), f2h(v0.z), f2h(v0.w),
                         f2h(v1.x), f2h(v1.y), f2h(v1.z), f2h(v1.w) };
            breg[kc] = q;
        }
    }

    const unsigned hload_base = (unsigned)((p*64 + g*16 + sb) * 1024 + sg*8);
    const unsigned hstore_off = (unsigned)((p*64 + g*16 + sb) * 1024 + s*64 + sg*4);
    const int col = s*64 + w*16 + lc;

    for (int step = 0; step < HALF_; step++) {
        const int tt = (p == 0) ? (2*step) : (step == 0 ? T_-1 : 2*step - 1);
        const int epw = step % 3 + 1;
        const int epv = (step + 2) % 3 + 1;   // prev step's epw
        f32x4 acc = (f32x4){0.f, 0.f, 0.f, 0.f};
        unsigned giu[4]; unsigned ob[4];

        if (step) {
            // 8 x 16B loads of this group's h (contiguous 32 KB per WG)
            bf16x8 hl[8];
            const short* hc = hbuf + (size_t)((step+1) & 1) * HBUF_HALF + hload_base;
#pragma unroll
            for (int c = 0; c < 8; c++)
                asm volatile("global_load_dwordx4 %0, %1, off sc0 sc1"
                             : "=v"(hl[c]) : "v"(hc + c*128) : "memory");
            // gi loads (device-scope; tag-checked after MFMA)
#pragma unroll
            for (int j = 0; j < 4; j++) {
                ob[j] = (unsigned)(((g*16 + lr*4 + j) * T_ + tt) * H_ + col);
                const float* ga = out + ob[j];
                asm volatile("global_load_dword %0, %1, off sc0 sc1"
                             : "=v"(giu[j]) : "v"(ga) : "memory");
            }
            const unsigned pat = (unsigned)((epv & 1) | (((epv >> 1) & 1) << 16));
            unsigned pend = 0;
            asm volatile("s_waitcnt vmcnt(4)" ::: "memory");   // h done, gi flying
            __builtin_amdgcn_sched_barrier(0);
#pragma unroll
            for (int c = 0; c < 8; c++) {
                u32x4 d = __builtin_bit_cast(u32x4, hl[c]);
                unsigned m = ((d[0] & 0x00010001u) ^ pat) | ((d[1] & 0x00010001u) ^ pat)
                           | ((d[2] & 0x00010001u) ^ pat) | ((d[3] & 0x00010001u) ^ pat);
                if (!__all(m == 0)) pend |= 1u << c;
            }
            while (pend) {   // retry stale slots until producer stores land
#pragma unroll
                for (int c = 0; c < 8; c++)
                    if (pend & (1u << c))
                        asm volatile("global_load_dwordx4 %0, %1, off sc0 sc1"
                                     : "=v"(hl[c]) : "v"(hc + c*128) : "memory");
                asm volatile("s_waitcnt vmcnt(0)" ::: "memory");
                __builtin_amdgcn_sched_barrier(0);
#pragma unroll
                for (int c = 0; c < 8; c++) {
                    if (pend & (1u << c)) {
                        u32x4 d = __builtin_bit_cast(u32x4, hl[c]);
                        unsigned m = ((d[0] & 0x00010001u) ^ pat) | ((d[1] & 0x00010001u) ^ pat)
                                   | ((d[2] & 0x00010001u) ^ pat) | ((d[3] & 0x00010001u) ^ pat);
                        if (__all(m == 0)) pend &= ~(1u << c);
                    }
                }
            }
            // stage to LDS, swizzled: granule g8 -> g8 ^ (row & 15)
#pragma unroll
            for (int c = 0; c < 8; c++) {
                bf16x4 lo = { hl[c][0], hl[c][1], hl[c][2], hl[c][3] };
                bf16x4 hi = { hl[c][4], hl[c][5], hl[c][6], hl[c][7] };
                const int g8 = (sg + c*16) * 2;
                *reinterpret_cast<bf16x4*>(&hB[sb*1024 + (((g8    ) ^ sb) << 2)]) = lo;
                *reinterpret_cast<bf16x4*>(&hB[sb*1024 + (((g8 + 1) ^ sb) << 2)]) = hi;
            }
            BAR();
            // fragment reads + MFMA (4 independent chains)
            f32x4 a0 = (f32x4){0,0,0,0}, a1 = (f32x4){0,0,0,0};
            f32x4 a2 = (f32x4){0,0,0,0}, a3 = (f32x4){0,0,0,0};
#pragma unroll
            for (int kc = 0; kc < 32; kc += 4) {
#pragma unroll
                for (int q = 0; q < 4; q++) {
                    const int k8 = (kc + q) * 8 + lr * 2;
                    bf16x4 lo = *reinterpret_cast<const bf16x4*>(&hB[lc*1024 + (((k8    ) ^ lc) << 2)]);
                    bf16x4 hi = *reinterpret_cast<const bf16x4*>(&hB[lc*1024 + (((k8 + 1) ^ lc) << 2)]);
                    bf16x8 hf = { lo[0], lo[1], lo[2], lo[3], hi[0], hi[1], hi[2], hi[3] };
                    f32x4& aq = (q == 0) ? a0 : (q == 1) ? a1 : (q == 2) ? a2 : a3;
                    aq = __builtin_amdgcn_mfma_f32_16x16x32_f16(
                        __builtin_bit_cast(f16x8, hf),
                        __builtin_bit_cast(f16x8, breg[kc + q]), aq, 0, 0, 0);
                }
            }
            acc = (a0 + a1) + (a2 + a3);
        } else {
#pragma unroll
            for (int j = 0; j < 4; j++) {
                ob[j] = (unsigned)(((g*16 + lr*4 + j) * T_ + tt) * H_ + col);
                const float* ga = out + ob[j];
                asm volatile("global_load_dword %0, %1, off sc0 sc1"
                             : "=v"(giu[j]) : "v"(ga) : "memory");
            }
        }

        // gi readiness poll: producers store every gi dword with LSB=1;
        // stale pre-launch content is h values with random LSBs -> rejected.
        asm volatile("s_waitcnt vmcnt(0)" ::: "memory");
        __builtin_amdgcn_sched_barrier(0);
        while (true) {
            unsigned okv = giu[0] & giu[1] & giu[2] & giu[3] & 1u;
            if (__all(okv != 0)) break;
#pragma unroll
            for (int j = 0; j < 4; j++) {
                const float* ga = out + ob[j];
                asm volatile("global_load_dword %0, %1, off sc0 sc1"
                             : "=v"(giu[j]) : "v"(ga) : "memory");
            }
            asm volatile("s_waitcnt vmcnt(0)" ::: "memory");
            __builtin_amdgcn_sched_barrier(0);
        }

        // h = tanh(acc + gi); fp16 + epoch LSB; transposes via LDS
        const unsigned short ebit = (unsigned short)((lc & 1) ? ((epw >> 1) & 1) : (epw & 1));
#pragma unroll
        for (int j = 0; j < 4; j++) {
            float gv = __builtin_bit_cast(float, giu[j]);
            float hv = tanh_fast(acc[j] + gv);
            unsigned short u = __builtin_bit_cast(unsigned short, (_Float16)hv);
            u = (unsigned short)((u & 0xFFFEu) | ebit);
            htr [(lr*4 + j)*68 + w*16 + lc] = (short)u;
            htrF[(lr*4 + j)*68 + w*16 + lc] = hv;
        }
        BAR();   // htr/htrF ready AND all waves done with hB reads

        if (step < HALF_ - 1) {   // producer store: one 8B dword-pair per thread
            bf16x4 v = *reinterpret_cast<bf16x4*>(&htr[sb*68 + sg*4]);
            short* hn = hbuf + (size_t)(step & 1) * HBUF_HALF + hstore_off;
            asm volatile("global_store_dwordx2 %0, %1, off sc0 sc1"
                         :: "v"(hn), "v"(v) : "memory");
        }

        // coalesced out[] store: one dwordx4/thread, contiguous 256B rows
        {
            f32x4 ov = *reinterpret_cast<f32x4*>(&htrF[sb*68 + sg*4]);
            float* op_ = out + (size_t)(((g*16 + sb) * T_ + tt) * H_ + s*64 + sg*4);
            asm volatile("global_store_dwordx4 %0, %1, off"
                         :: "v"(op_), "v"(ov) : "memory");
            if (p == 0 && step == HALF_ - 1) {
                float* fp_ = out + (size_t)B_*T_*H_ + (size_t)((g*16 + sb) * H_ + s*64 + sg*4);
                asm volatile("global_store_dwordx4 %0, %1, off"
                             :: "v"(fp_), "v"(ov) : "memory");
            }
        }
    }
}

extern "C" void kernel_launch(void* const* d_in, const int* in_sizes, int n_in,
                              void* d_out, int out_size, void* d_ws, size_t ws_size,
                              hipStream_t stream) {
    const float* X   = (const float*)d_in[0];
    const float* Wih = (const float*)d_in[1];
    const float* Whh = (const float*)d_in[2];
    const float* bih = (const float*)d_in[3];
    const float* bhh = (const float*)d_in[4];
    float* out = (float*)d_out;

    short* hbuf = (short*)d_ws;   // [2 dbuf][2 p][64 b][1024] fp16 = 512 KB

    // Epoch 0 is invalid: zeroing hbuf rejects cross-graph-replay leftovers.
    hipMemsetAsync(hbuf, 0, (size_t)2 * HBUF_HALF * 2, stream);
    pre_gemm<<<dim3(1024), dim3(256), 0, stream>>>(X, Wih, bih, bhh, out);
    fused_rnn<<<dim3(NWG_SCAN + NWG_GEMM_REST), dim3(256), 0, stream>>>(
        X, Wih, bih, bhh, Whh, out, hbuf);
}

// Round 12
// 1893.887 us; speedup vs baseline: 1.0292x; 1.0292x over previous
//
#include <hip/hip_runtime.h>

#define B_    64
#define T_    1024
#define H_    1024
#define HALF_ 512
#define NWG_SCAN 128
#define HBUF_HALF 131072   // shorts per double-buffer half: 2*64*1024

typedef short bf16x8 __attribute__((ext_vector_type(8)));
typedef short bf16x4 __attribute__((ext_vector_type(4)));
typedef _Float16 f16x8 __attribute__((ext_vector_type(8)));
typedef float f32x4  __attribute__((ext_vector_type(4)));
typedef unsigned int u32x4 __attribute__((ext_vector_type(4)));
typedef unsigned int u32x2 __attribute__((ext_vector_type(2)));

__device__ __forceinline__ short f2h(float f) {
    return (short)__builtin_bit_cast(unsigned short, (_Float16)f);
}

// Packed f32x4 -> bf16x4 via v_cvt_pk_bf16_f32 (RNE; 2 instrs replace ~16
// VALU ops of manual round-and-shift). No builtin on gfx950 -> inline asm.
__device__ __forceinline__ bf16x4 pk4(f32x4 v) {
    unsigned w0, w1;
    asm("v_cvt_pk_bf16_f32 %0, %1, %2" : "=v"(w0) : "v"(v.x), "v"(v.y));
    asm("v_cvt_pk_bf16_f32 %0, %1, %2" : "=v"(w1) : "v"(v.z), "v"(v.w));
    u32x2 r; r[0] = w0; r[1] = w1;
    return __builtin_bit_cast(bf16x4, r);
}

__device__ __forceinline__ float tanh_fast(float x) {
    return 1.0f - 2.0f / (__expf(2.0f * x) + 1.0f);
}

// LDS-only barrier: hipcc's __syncthreads emits s_waitcnt vmcnt(0) before
// s_barrier; this waits LDS ops only, vmem stays in flight.
#define BAR() do { \
    __builtin_amdgcn_sched_barrier(0); \
    asm volatile("s_waitcnt lgkmcnt(0)" ::: "memory"); \
    __builtin_amdgcn_sched_barrier(0); \
    __builtin_amdgcn_s_barrier(); \
    __builtin_amdgcn_sched_barrier(0); \
} while (0)

// ---------------- Phase 1: gi = bf16(x) @ bf16(W_ih)^T + (b_ih + b_hh) --------
// R7 structure; staging conversion switched to v_cvt_pk_bf16_f32 (the 415 TF
// ceiling of this structure is VALU-staging-bound, and manual f2bf rounding
// was the largest staging VALU item).
__global__ __launch_bounds__(256) void gi_gemm(
        const float* __restrict__ X, const float* __restrict__ Wih,
        const float* __restrict__ bih, const float* __restrict__ bhh,
        float* __restrict__ out) {
    __shared__ short As[128][40];
    __shared__ short Bs[128][40];
    const int bid = blockIdx.x;
    const int tn = bid & 7;
    const int tm = bid >> 3;
    const int tid = threadIdx.x;
    const int l  = tid & 63;
    const int w  = tid >> 6;
    const int wr = w >> 1, wc = w & 1;
    const int lc = l & 15,  lr = l >> 4;

    const float* Ab = X   + (size_t)tm * 128 * 1024;
    const float* Bb = Wih + (size_t)tn * 128 * 1024;
    const int srow = tid >> 3;
    const int sc4  = (tid & 7) * 4;

    f32x4 acc[4][4];
#pragma unroll
    for (int m = 0; m < 4; m++)
#pragma unroll
        for (int n = 0; n < 4; n++) acc[m][n] = (f32x4){0.f, 0.f, 0.f, 0.f};

    f32x4 ra[4], rb[4];
#pragma unroll
    for (int c = 0; c < 4; c++) {
        ra[c] = *reinterpret_cast<const f32x4*>(Ab + (size_t)(srow + 32*c) * 1024 + sc4);
        rb[c] = *reinterpret_cast<const f32x4*>(Bb + (size_t)(srow + 32*c) * 1024 + sc4);
    }

    for (int k0 = 0; k0 < 1024; k0 += 32) {
        __syncthreads();
#pragma unroll
        for (int c = 0; c < 4; c++) {
            *reinterpret_cast<bf16x4*>(&As[srow + 32*c][sc4]) = pk4(ra[c]);
            *reinterpret_cast<bf16x4*>(&Bs[srow + 32*c][sc4]) = pk4(rb[c]);
        }
        __syncthreads();
        if (k0 + 32 < 1024) {
            const float* Ak = Ab + k0 + 32;
            const float* Bk = Bb + k0 + 32;
#pragma unroll
            for (int c = 0; c < 4; c++) {
                ra[c] = *reinterpret_cast<const f32x4*>(Ak + (size_t)(srow + 32*c) * 1024 + sc4);
                rb[c] = *reinterpret_cast<const f32x4*>(Bk + (size_t)(srow + 32*c) * 1024 + sc4);
            }
        }
        bf16x8 af[4], bfr[4];
#pragma unroll
        for (int m = 0; m < 4; m++)
            af[m] = *reinterpret_cast<bf16x8*>(&As[wr*64 + m*16 + lc][lr*8]);
#pragma unroll
        for (int n = 0; n < 4; n++)
            bfr[n] = *reinterpret_cast<bf16x8*>(&Bs[wc*64 + n*16 + lc][lr*8]);
#pragma unroll
        for (int m = 0; m < 4; m++)
#pragma unroll
            for (int n = 0; n < 4; n++)
                acc[m][n] = __builtin_amdgcn_mfma_f32_16x16x32_bf16(af[m], bfr[n], acc[m][n], 0, 0, 0);
    }

#pragma unroll
    for (int n = 0; n < 4; n++) {
        const int col = tn*128 + wc*64 + n*16 + lc;
        const float bs = bih[col] + bhh[col];
#pragma unroll
        for (int m = 0; m < 4; m++) {
            const int row0 = tm*128 + wr*64 + m*16 + lr*4;
#pragma unroll
            for (int j = 0; j < 4; j++)
                out[(size_t)(row0 + j) * 1024 + col] = acc[m][n][j] + bs;
        }
    }
}

// ---------------- Phase 2: batch-partitioned barrier-free scan ---------------
// R7 proven version (1605 us) + adaptive pre-issue delay: producers/consumers
// run in lockstep, so the first h poll is usually issued BEFORE the stores
// reach the IC -> guaranteed miss -> the step pays 2 IC round trips instead
// of 1. Each wave AIMD-tunes a sleep (dly x s_sleep(1) ~ 28ns) inserted
// before the h-load issue: retry seen -> dly += 4, clean -> dly -= 1
// (equilibrium ~20% retry). Pure timing change; epoch-LSB protocol unchanged
// (epoch = step%3+1, 0 invalid; hbuf zeroed per launch).
__global__ __launch_bounds__(256, 1) void rnn_scan(
        const float* __restrict__ Whh, float* __restrict__ out,
        short* __restrict__ hbuf) {
    __shared__ short hB[16 * 1024];   // h stage [16 batch][1024 k], swizzled
    __shared__ short htr[16 * 68];    // fp16+epoch transpose [batch][col+pad]
    __shared__ float htrF[16 * 68];   // f32 transpose for coalesced out stores
    const int wg = blockIdx.x;
    const int p  = wg >> 6;           // parity
    const int g  = (wg >> 4) & 3;     // batch group (16 batches)
    const int s  = wg & 15;           // col slice (64 cols)
    const int tid = threadIdx.x;
    const int l  = tid & 63;
    const int w  = tid >> 6;
    const int lc = l & 15, lr = l >> 4;
    const int sb = tid >> 4;          // staging batch row 0..15
    const int sg = tid & 15;          // staging granule index

    // W_hh rows [s*64 + w*16 + lc], fp32 -> fp16, direct to 128 VGPRs
    bf16x8 breg[32];
    {
        const float* wrow = Whh + (size_t)(s*64 + w*16 + lc) * 1024;
#pragma unroll
        for (int kc = 0; kc < 32; kc++) {
            f32x4 v0 = *reinterpret_cast<const f32x4*>(wrow + kc*32 + lr*8);
            f32x4 v1 = *reinterpret_cast<const f32x4*>(wrow + kc*32 + lr*8 + 4);
            bf16x8 q = { f2h(v0.x), f2h(v0.y), f2h(v0.z), f2h(v0.w),
                         f2h(v1.x), f2h(v1.y), f2h(v1.z), f2h(v1.w) };
            breg[kc] = q;
        }
    }

    const unsigned hload_base = (unsigned)((p*64 + g*16 + sb) * 1024 + sg*8);
    const unsigned hstore_off = (unsigned)((p*64 + g*16 + sb) * 1024 + s*64 + sg*4);
    const int col = s*64 + w*16 + lc;

    int dly = 8;   // adaptive pre-issue delay, units of s_sleep(1) (~28 ns)

    for (int step = 0; step < HALF_; step++) {
        const int tt = (p == 0) ? (2*step) : (step == 0 ? T_-1 : 2*step - 1);
        const int epw = step % 3 + 1;
        const int epv = (step + 2) % 3 + 1;   // prev step's epw
        f32x4 acc = (f32x4){0.f, 0.f, 0.f, 0.f};
        float gi[4]; unsigned ob[4];

        if (step) {
            // adaptive delay: let the producers' stores reach the IC before
            // the first poll, converting miss+retry (2 RT) into hit (1 RT)
            for (int i = 0; i < dly; i++)
                asm volatile("s_sleep 1" ::: "memory");
            // 8 x 16B loads of this group's h (contiguous 32 KB per WG)
            bf16x8 hl[8];
            const short* hc = hbuf + (size_t)((step+1) & 1) * HBUF_HALF + hload_base;
#pragma unroll
            for (int c = 0; c < 8; c++)
                asm volatile("global_load_dwordx4 %0, %1, off sc0 sc1"
                             : "=v"(hl[c]) : "v"(hc + c*128) : "memory");
            // gi loads (normal cached; overlap with h flight)
#pragma unroll
            for (int j = 0; j < 4; j++) {
                ob[j] = (unsigned)(((g*16 + lr*4 + j) * T_ + tt) * H_ + col);
                gi[j] = out[ob[j]];
            }
            const unsigned pat = (unsigned)((epv & 1) | (((epv >> 1) & 1) << 16));
            unsigned pend = 0;
            asm volatile("s_waitcnt vmcnt(4)" ::: "memory");   // h done, gi flying
            __builtin_amdgcn_sched_barrier(0);
#pragma unroll
            for (int c = 0; c < 8; c++) {
                u32x4 d = __builtin_bit_cast(u32x4, hl[c]);
                unsigned m = ((d[0] & 0x00010001u) ^ pat) | ((d[1] & 0x00010001u) ^ pat)
                           | ((d[2] & 0x00010001u) ^ pat) | ((d[3] & 0x00010001u) ^ pat);
                if (!__all(m == 0)) pend |= 1u << c;
            }
            const int hadRetry = (pend != 0);   // wave-uniform (set via __all)
            while (pend) {   // retry stale slots until producer stores land
#pragma unroll
                for (int c = 0; c < 8; c++)
                    if (pend & (1u << c))
                        asm volatile("global_load_dwordx4 %0, %1, off sc0 sc1"
                                     : "=v"(hl[c]) : "v"(hc + c*128) : "memory");
                asm volatile("s_waitcnt vmcnt(0)" ::: "memory");
                __builtin_amdgcn_sched_barrier(0);
#pragma unroll
                for (int c = 0; c < 8; c++) {
                    if (pend & (1u << c)) {
                        u32x4 d = __builtin_bit_cast(u32x4, hl[c]);
                        unsigned m = ((d[0] & 0x00010001u) ^ pat) | ((d[1] & 0x00010001u) ^ pat)
                                   | ((d[2] & 0x00010001u) ^ pat) | ((d[3] & 0x00010001u) ^ pat);
                        if (__all(m == 0)) pend &= ~(1u << c);
                    }
                }
            }
            // AIMD update (per-wave)
            dly = hadRetry ? (dly > 44 ? 48 : dly + 4) : (dly ? dly - 1 : 0);
            // stage to LDS, swizzled: granule g8 -> g8 ^ (row & 15)
#pragma unroll
            for (int c = 0; c < 8; c++) {
                bf16x4 lo = { hl[c][0], hl[c][1], hl[c][2], hl[c][3] };
                bf16x4 hi = { hl[c][4], hl[c][5], hl[c][6], hl[c][7] };
                const int g8 = (sg + c*16) * 2;
                *reinterpret_cast<bf16x4*>(&hB[sb*1024 + (((g8    ) ^ sb) << 2)]) = lo;
                *reinterpret_cast<bf16x4*>(&hB[sb*1024 + (((g8 + 1) ^ sb) << 2)]) = hi;
            }
            BAR();
            // fragment reads + MFMA (4 independent chains)
            f32x4 a0 = (f32x4){0,0,0,0}, a1 = (f32x4){0,0,0,0};
            f32x4 a2 = (f32x4){0,0,0,0}, a3 = (f32x4){0,0,0,0};
#pragma unroll
            for (int kc = 0; kc < 32; kc += 4) {
#pragma unroll
                for (int q = 0; q < 4; q++) {
                    const int k8 = (kc + q) * 8 + lr * 2;
                    bf16x4 lo = *reinterpret_cast<const bf16x4*>(&hB[lc*1024 + (((k8    ) ^ lc) << 2)]);
                    bf16x4 hi = *reinterpret_cast<const bf16x4*>(&hB[lc*1024 + (((k8 + 1) ^ lc) << 2)]);
                    bf16x8 hf = { lo[0], lo[1], lo[2], lo[3], hi[0], hi[1], hi[2], hi[3] };
                    f32x4& aq = (q == 0) ? a0 : (q == 1) ? a1 : (q == 2) ? a2 : a3;
                    aq = __builtin_amdgcn_mfma_f32_16x16x32_f16(
                        __builtin_bit_cast(f16x8, hf),
                        __builtin_bit_cast(f16x8, breg[kc + q]), aq, 0, 0, 0);
                }
            }
            acc = (a0 + a1) + (a2 + a3);
        } else {
#pragma unroll
            for (int j = 0; j < 4; j++) {
                ob[j] = (unsigned)(((g*16 + lr*4 + j) * T_ + tt) * H_ + col);
                gi[j] = out[ob[j]];
            }
        }

        // h = tanh(acc + gi); fp16 + epoch LSB; transposes via LDS
        const unsigned short ebit = (unsigned short)((lc & 1) ? ((epw >> 1) & 1) : (epw & 1));
#pragma unroll
        for (int j = 0; j < 4; j++) {
            float hv = tanh_fast(acc[j] + gi[j]);
            unsigned short u = __builtin_bit_cast(unsigned short, (_Float16)hv);
            u = (unsigned short)((u & 0xFFFEu) | ebit);
            htr [(lr*4 + j)*68 + w*16 + lc] = (short)u;
            htrF[(lr*4 + j)*68 + w*16 + lc] = hv;
        }
        BAR();   // htr/htrF ready AND all waves done with hB reads

        if (step < HALF_ - 1) {   // producer store: one 8B dword-pair per thread
            bf16x4 v = *reinterpret_cast<bf16x4*>(&htr[sb*68 + sg*4]);
            short* hn = hbuf + (size_t)(step & 1) * HBUF_HALF + hstore_off;
            asm volatile("global_store_dwordx2 %0, %1, off sc0 sc1"
                         :: "v"(hn), "v"(v) : "memory");
        }

        // coalesced out[] store: one dwordx4/thread, contiguous 256B rows
        {
            f32x4 ov = *reinterpret_cast<f32x4*>(&htrF[sb*68 + sg*4]);
            float* op_ = out + (size_t)(((g*16 + sb) * T_ + tt) * H_ + s*64 + sg*4);
            asm volatile("global_store_dwordx4 %0, %1, off"
                         :: "v"(op_), "v"(ov) : "memory");
            if (p == 0 && step == HALF_ - 1) {
                float* fp_ = out + (size_t)B_*T_*H_ + (size_t)((g*16 + sb) * H_ + s*64 + sg*4);
                asm volatile("global_store_dwordx4 %0, %1, off"
                             :: "v"(fp_), "v"(ov) : "memory");
            }
        }
    }
}

extern "C" void kernel_launch(void* const* d_in, const int* in_sizes, int n_in,
                              void* d_out, int out_size, void* d_ws, size_t ws_size,
                              hipStream_t stream) {
    const float* X   = (const float*)d_in[0];
    const float* Wih = (const float*)d_in[1];
    const float* Whh = (const float*)d_in[2];
    const float* bih = (const float*)d_in[3];
    const float* bhh = (const float*)d_in[4];
    float* out = (float*)d_out;

    short* hbuf = (short*)d_ws;   // [2 dbuf][2 p][64 b][1024] fp16 = 512 KB

    // Epoch 0 is invalid: zeroing hbuf rejects cross-graph-replay leftovers.
    hipMemsetAsync(hbuf, 0, (size_t)2 * HBUF_HALF * 2, stream);
    gi_gemm<<<dim3(4096), dim3(256), 0, stream>>>(X, Wih, bih, bhh, out);
    rnn_scan<<<dim3(NWG_SCAN), dim3(256), 0, stream>>>(Whh, out, hbuf);
}